// Round 1
// baseline (103.197 us; speedup 1.0000x reference)
//
#include <hip/hip_runtime.h>

#define KW 7
#define PAD 3
#define TW 64
#define TH 64
#define LW (TW + KW - 1)   // 70
#define LH (TH + KW - 1)   // 70
#define LSTRIDE 70         // floats; rows 8B-aligned, 280%32=24 spreads banks across tcy

__global__ __launch_bounds__(256)
void conv7x7_kernel(const float* __restrict__ x, const float* __restrict__ w,
                    float* __restrict__ out, int H, int W, int tilesx, int tilesy) {
    __shared__ float tile[LH * LSTRIDE];

    const int bi   = blockIdx.x;
    const int tpi  = tilesx * tilesy;
    const int n    = bi / tpi;
    const int trem = bi % tpi;
    const int ty0  = (trem / tilesx) * TH;
    const int tx0  = (trem % tilesx) * TW;

    const float* xn = x + (size_t)n * H * W;

    // Uniform weight load -> expect SGPRs
    float wr[49];
#pragma unroll
    for (int i = 0; i < 49; ++i) wr[i] = w[i];

    // Stage 70x70 input tile (with halo, zero-padded at image borders)
    const int t = threadIdx.x;
    for (int idx = t; idx < LH * LW; idx += 256) {
        const int r  = idx / LW;
        const int c  = idx % LW;
        const int gr = ty0 + r - PAD;
        const int gc = tx0 + c - PAD;
        float v = 0.f;
        if (gr >= 0 && gr < H && gc >= 0 && gc < W)
            v = xn[(size_t)gr * W + gc];
        tile[r * LSTRIDE + c] = v;
    }
    __syncthreads();

    // Each thread computes a 4x4 output micro-tile
    const int tcx = t & 15;
    const int tcy = t >> 4;
    const int ci  = tcx * 4;   // local col of first output
    const int ri  = tcy * 4;   // local row of first output

    float acc[4][4];
#pragma unroll
    for (int i = 0; i < 4; ++i)
#pragma unroll
        for (int j = 0; j < 4; ++j) acc[i][j] = 0.f;

#pragma unroll
    for (int r = 0; r < 10; ++r) {          // window rows ri..ri+9
        float v[10];
        const float* lp = &tile[(ri + r) * LSTRIDE + ci];
#pragma unroll
        for (int p = 0; p < 5; ++p) {       // 5 x ds_read_b64
            const float2 tmp = *reinterpret_cast<const float2*>(lp + 2 * p);
            v[2 * p]     = tmp.x;
            v[2 * p + 1] = tmp.y;
        }
#pragma unroll
        for (int i = 0; i < 4; ++i) {
            const int di = r - i;
            if (di >= 0 && di < KW) {
#pragma unroll
                for (int j = 0; j < 4; ++j) {
#pragma unroll
                    for (int dj = 0; dj < KW; ++dj)
                        acc[i][j] += v[j + dj] * wr[di * KW + dj];
                }
            }
        }
    }

    float* on = out + (size_t)n * H * W;
#pragma unroll
    for (int i = 0; i < 4; ++i) {
        const int gr = ty0 + ri + i;
        const float4 val = make_float4(acc[i][0], acc[i][1], acc[i][2], acc[i][3]);
        *reinterpret_cast<float4*>(&on[(size_t)gr * W + tx0 + ci]) = val;
    }
}

extern "C" void kernel_launch(void* const* d_in, const int* in_sizes, int n_in,
                              void* d_out, int out_size, void* d_ws, size_t ws_size,
                              hipStream_t stream) {
    const float* x = (const float*)d_in[0];
    const float* w = (const float*)d_in[1];
    float* out = (float*)d_out;

    const int H = 512, W = 512, N = 128;
    const int tilesx = W / TW;   // 8
    const int tilesy = H / TH;   // 8
    const int nblocks = N * tilesx * tilesy;   // 8192

    conv7x7_kernel<<<nblocks, 256, 0, stream>>>(x, w, out, H, W, tilesx, tilesy);
}

// Round 2
// 75.894 us; speedup vs baseline: 1.3598x; 1.3598x over previous
//
#include <hip/hip_runtime.h>

#define KW 7
#define TW 64
#define TH 64
#define LH 70          // TH + 6 halo rows
#define LWIDE 72       // tile cols tx0-4 .. tx0+67 (16B-aligned both ends)
#define NCHUNK 18      // float4 chunks per tile row

__global__ __launch_bounds__(256)
void conv7x7_kernel(const float* __restrict__ x, const float* __restrict__ w,
                    float* __restrict__ out) {
    __shared__ float tile[LH * LWIDE];   // 20160 B -> 8 blocks/CU by LDS

    const int H = 512, W = 512;
    const int bi   = blockIdx.x;
    const int n    = bi >> 6;            // 64 tiles per image
    const int trem = bi & 63;
    const int ty0  = (trem >> 3) * TH;
    const int tx0  = (trem & 7) * TW;

    const float* xn = x + (size_t)n * H * W;

    // Uniform weight load -> SGPRs
    float wr[49];
#pragma unroll
    for (int i = 0; i < 49; ++i) wr[i] = w[i];

    // ---- Stage 70x72 tile as float4 chunks (all aligned, full-or-zero OOB) ----
    const int t = threadIdx.x;
    for (int idx = t; idx < LH * NCHUNK; idx += 256) {
        const int tr = idx / NCHUNK;
        const int ci = idx - tr * NCHUNK;
        const int gr = ty0 + tr - 3;
        const int gc = tx0 + 4 * ci - 4;
        float4 v = make_float4(0.f, 0.f, 0.f, 0.f);
        if (gr >= 0 && gr < H && gc >= 0 && gc + 3 < W)
            v = *reinterpret_cast<const float4*>(&xn[(size_t)gr * W + gc]);
        *reinterpret_cast<float4*>(&tile[tr * LWIDE + 4 * ci]) = v;
    }
    __syncthreads();

    // ---- Compute: thread (q, rg) -> output cols 4q..4q+3, rows 4rg..4rg+3 ----
    const int q  = t & 15;
    const int rg = t >> 4;
    const int c0 = 4 * q;    // tile dword col of v[0]; out global col base = tx0 + c0
    const int r0 = 4 * rg;   // first tile row of window = first output row (local)

    float acc[4][4];
#pragma unroll
    for (int i = 0; i < 4; ++i)
#pragma unroll
        for (int j = 0; j < 4; ++j) acc[i][j] = 0.f;

#pragma unroll
    for (int s = 0; s < 10; ++s) {       // input rows r0+s (tile coords)
        const float* lp = &tile[(r0 + s) * LWIDE + c0];
        float v[12];
#pragma unroll
        for (int p = 0; p < 3; ++p) {    // 3 x ds_read_b128, bank-uniform
            const float4 tmp = *reinterpret_cast<const float4*>(lp + 4 * p);
            v[4 * p]     = tmp.x;
            v[4 * p + 1] = tmp.y;
            v[4 * p + 2] = tmp.z;
            v[4 * p + 3] = tmp.w;
        }
#pragma unroll
        for (int i = 0; i < 4; ++i) {
            const int k = s - i;         // weight row
            if (k >= 0 && k < KW) {
#pragma unroll
                for (int j = 0; j < 4; ++j)
#pragma unroll
                    for (int dj = 0; dj < KW; ++dj)
                        acc[i][j] += v[1 + j + dj] * wr[k * KW + dj];
            }
        }
    }

    // ---- Store 4 rows x float4 ----
    float* on = out + (size_t)n * H * W;
#pragma unroll
    for (int i = 0; i < 4; ++i) {
        const float4 val = make_float4(acc[i][0], acc[i][1], acc[i][2], acc[i][3]);
        *reinterpret_cast<float4*>(&on[(size_t)(ty0 + r0 + i) * W + tx0 + c0]) = val;
    }
}

extern "C" void kernel_launch(void* const* d_in, const int* in_sizes, int n_in,
                              void* d_out, int out_size, void* d_ws, size_t ws_size,
                              hipStream_t stream) {
    const float* x = (const float*)d_in[0];
    const float* w = (const float*)d_in[1];
    float* out = (float*)d_out;

    const int N = 128;
    const int nblocks = N * 64;   // 8192
    conv7x7_kernel<<<nblocks, 256, 0, stream>>>(x, w, out);
}

// Round 3
// 75.487 us; speedup vs baseline: 1.3671x; 1.0054x over previous
//
#include <hip/hip_runtime.h>

#define KW 7
#define TW 64
#define TH 64
#define LH 70          // TH + 6 halo rows
#define LWIDE 72       // tile cols tx0-4 .. tx0+67 (16B-aligned both ends)
#define NCHUNK 18      // float4 chunks per tile row
#define NCHUNKS_TOT (LH * NCHUNK)   // 1260

__global__ __launch_bounds__(256)
void conv7x7_kernel(const float* __restrict__ x, const float* __restrict__ w,
                    float* __restrict__ out) {
    __shared__ float tile[LH * LWIDE];   // 20160 B -> exactly 8 blocks/CU

    const int H = 512, W = 512;
    const int bi   = blockIdx.x;
    const int n    = bi >> 6;            // 64 tiles per image
    const int trem = bi & 63;
    const int ty0  = (trem >> 3) * TH;
    const int tx0  = (trem & 7) * TW;

    const float* xn = x + (size_t)n * H * W;

    // Wave-uniform weights, forced into SGPRs (frees ~49 VGPRs)
    float wr[49];
#pragma unroll
    for (int i = 0; i < 49; ++i)
        wr[i] = __uint_as_float((unsigned)__builtin_amdgcn_readfirstlane(
                    (int)__float_as_uint(w[i])));

    const int t = threadIdx.x;
    const bool interior = (tx0 != 0) && (tx0 != W - TW) &&
                          (ty0 != 0) && (ty0 != H - TH);

    if (interior) {
        // No border checks: rows ty0-3..ty0+66, cols tx0-4..tx0+67 all valid
        const float* src0 = xn + (size_t)(ty0 - 3) * W + (tx0 - 4);
#pragma unroll
        for (int k = 0; k < 5; ++k) {
            const int idx = t + 256 * k;
            if (k < 4 || idx < NCHUNKS_TOT) {
                const int tr = idx / NCHUNK;
                const int ci = idx - tr * NCHUNK;
                const float4 v = *reinterpret_cast<const float4*>(
                    src0 + (size_t)tr * W + 4 * ci);
                *reinterpret_cast<float4*>(&tile[tr * LWIDE + 4 * ci]) = v;
            }
        }
    } else {
#pragma unroll
        for (int k = 0; k < 5; ++k) {
            const int idx = t + 256 * k;
            if (k < 4 || idx < NCHUNKS_TOT) {
                const int tr = idx / NCHUNK;
                const int ci = idx - tr * NCHUNK;
                const int gr = ty0 + tr - 3;
                const int gc = tx0 + 4 * ci - 4;
                float4 v = make_float4(0.f, 0.f, 0.f, 0.f);
                if (gr >= 0 && gr < H && gc >= 0 && gc + 3 < W)
                    v = *reinterpret_cast<const float4*>(&xn[(size_t)gr * W + gc]);
                *reinterpret_cast<float4*>(&tile[tr * LWIDE + 4 * ci]) = v;
            }
        }
    }
    __syncthreads();

    // ---- Compute: thread (q, rg) -> output cols 4q..4q+3, rows 4rg..4rg+3 ----
    const int q  = t & 15;
    const int rg = t >> 4;
    const int c0 = 4 * q;
    const int r0 = 4 * rg;

    float acc[4][4];
#pragma unroll
    for (int i = 0; i < 4; ++i)
#pragma unroll
        for (int j = 0; j < 4; ++j) acc[i][j] = 0.f;

    const float* lp = &tile[r0 * LWIDE + c0];
#pragma unroll
    for (int s = 0; s < 10; ++s) {       // input rows r0+s (tile coords)
        float v[12];
#pragma unroll
        for (int p = 0; p < 3; ++p) {    // 3 x ds_read_b128, bank-uniform
            const float4 tmp = *reinterpret_cast<const float4*>(lp + 4 * p);
            v[4 * p]     = tmp.x;
            v[4 * p + 1] = tmp.y;
            v[4 * p + 2] = tmp.z;
            v[4 * p + 3] = tmp.w;
        }
        lp += LWIDE;
#pragma unroll
        for (int i = 0; i < 4; ++i) {
            const int kk = s - i;        // weight row
            if (kk >= 0 && kk < KW) {
#pragma unroll
                for (int j = 0; j < 4; ++j)
#pragma unroll
                    for (int dj = 0; dj < KW; ++dj)
                        acc[i][j] += v[1 + j + dj] * wr[kk * KW + dj];
            }
        }
    }

    // ---- Store 4 rows x float4 ----
    float* on = out + (size_t)n * H * W;
#pragma unroll
    for (int i = 0; i < 4; ++i) {
        const float4 val = make_float4(acc[i][0], acc[i][1], acc[i][2], acc[i][3]);
        *reinterpret_cast<float4*>(&on[(size_t)(ty0 + r0 + i) * W + tx0 + c0]) = val;
    }
}

extern "C" void kernel_launch(void* const* d_in, const int* in_sizes, int n_in,
                              void* d_out, int out_size, void* d_ws, size_t ws_size,
                              hipStream_t stream) {
    const float* x = (const float*)d_in[0];
    const float* w = (const float*)d_in[1];
    float* out = (float*)d_out;

    const int N = 128;
    const int nblocks = N * 64;   // 8192
    conv7x7_kernel<<<nblocks, 256, 0, stream>>>(x, w, out);
}